// Round 12
// baseline (190.232 us; speedup 1.0000x reference)
//
#include <hip/hip_runtime.h>

typedef __attribute__((ext_vector_type(8))) short short8;
typedef __attribute__((ext_vector_type(4))) short short4v;
typedef __attribute__((ext_vector_type(4))) float float4v;

#define T_SEQ 2048
#define CDIM 1024
#define NHEAD 16
#define HDIM 64
#define PROW 72  // proj LDS row stride (shorts), BK=64 + pad

__device__ __forceinline__ unsigned short f2bf(float f) {
    unsigned u = __builtin_bit_cast(unsigned, f);
    u += 0x7FFF + ((u >> 16) & 1);
    return (unsigned short)(u >> 16);
}

// async global->LDS, 16B per lane. LDS dest wave-uniform base + lane*16B.
__device__ __forceinline__ void gload16(const unsigned short* g,
                                        unsigned short* l) {
    __builtin_amdgcn_global_load_lds(
        (const __attribute__((address_space(1))) unsigned int*)g,
        (__attribute__((address_space(3))) unsigned int*)l, 16, 0, 0);
}

// raw barrier WITHOUT the implicit vmcnt(0) drain of __syncthreads.
__device__ __forceinline__ void phase_barrier() {
    __builtin_amdgcn_sched_barrier(0);
    __builtin_amdgcn_s_barrier();
    __builtin_amdgcn_sched_barrier(0);
}

// ---------------- fused preprocessing: convert + 2 transposes -------------
__global__ __launch_bounds__(256) void preproc(
    const float* __restrict__ x, unsigned short* __restrict__ xb,
    const float* __restrict__ Wa, unsigned short* __restrict__ WaT,
    const float* __restrict__ Wp, unsigned short* __restrict__ WpT) {
    int bid = blockIdx.x, tid = threadIdx.x;
    if (bid < 4096) {
        int i = bid * 256 + tid;
        float4 v = ((const float4*)x)[i];
        ushort4 o;
        o.x = f2bf(v.x); o.y = f2bf(v.y); o.z = f2bf(v.z); o.w = f2bf(v.w);
        ((ushort4*)xb)[i] = o;
        return;
    }
    __shared__ float tile[32][33];
    const float* in;
    unsigned short* out;
    int N, b;
    if (bid < 4096 + 3072) {
        b = bid - 4096; in = Wa; out = WaT; N = 3072;
    } else {
        b = bid - 7168; in = Wp; out = WpT; N = 1024;
    }
    const int K = 1024;
    int kb = (b & 31) * 32, nb = (b >> 5) * 32;
    int tx = tid & 31, ty = tid >> 5;  // ty 0..7
    for (int r = 0; r < 4; r++)
        tile[ty + r * 8][tx] = in[(size_t)(kb + ty + r * 8) * N + nb + tx];
    __syncthreads();
    for (int r = 0; r < 4; r++)
        out[(size_t)(nb + ty + r * 8) * K + kb + tx] = f2bf(tile[tx][ty + r * 8]);
}

// ---------------- QKV GEMM: 128x128, BK=32, 3-buffer counted-vmcnt --------
// R6 proven version (49.2-49.6us), default block order. R11's XCD swizzle
// REGRESSED (FETCH 40->54.5MB, +2us): contiguous 96-block chunks/XCD need
// A 1MB + B 6MB = 7MB > 4MB L2 (B thrash); default round-robin shares
// B panels across XCDs better. T1 closed for this kernel.
__global__ __launch_bounds__(256) void gemm_qkv(
    const unsigned short* __restrict__ A, const unsigned short* __restrict__ Bt,
    unsigned short* __restrict__ dK, unsigned short* __restrict__ dQ,
    unsigned short* __restrict__ dV) {
    const int K = 1024;
    const int NITER = K / 32;  // 32
    __shared__ unsigned short sA[3][128 * 32];
    __shared__ unsigned short sB[3][128 * 32];
    int tid = threadIdx.x, wave = tid >> 6, lane = tid & 63;
    int quad = lane >> 4, l16 = lane & 15;
    int wm = wave >> 1, wn = wave & 1;
    int blockM = blockIdx.y * 128, blockN = blockIdx.x * 128;
    bool swapAB = (blockN >= 2048);  // V part: produce C^T

    const unsigned short* gA = A + (size_t)blockM * K;
    const unsigned short* gB = Bt + (size_t)blockN * K;

    int srow = wave * 32 + (lane >> 2);
    int scol = (lane & 3) * 8;
    const unsigned short* pa0 = gA + (size_t)srow * K + scol;
    const unsigned short* pa1 = pa0 + (size_t)16 * K;
    const unsigned short* pb0 = gB + (size_t)srow * K + scol;
    const unsigned short* pb1 = pb0 + (size_t)16 * K;
    int lo0 = (wave * 32) * 32;
    int lo1 = (wave * 32 + 16) * 32;

    float4v acc[4][4] = {};
    int aoff = (wm * 64 + l16) * 32 + quad * 8;
    int boff = (wn * 64 + l16) * 32 + quad * 8;

    for (int t = 0; t < 2; t++) {
        int kb = t * 32;
        gload16(pa0 + kb, sA[t] + lo0);
        gload16(pa1 + kb, sA[t] + lo1);
        gload16(pb0 + kb, sB[t] + lo0);
        gload16(pb1 + kb, sB[t] + lo1);
    }
    asm volatile("s_waitcnt vmcnt(4)" ::: "memory");
    phase_barrier();

#pragma unroll
    for (int it = 0; it < NITER; it++) {
        int cur = it % 3;
        if (it + 2 < NITER) {
            int kb = (it + 2) * 32;
            int nb = (it + 2) % 3;
            gload16(pa0 + kb, sA[nb] + lo0);
            gload16(pa1 + kb, sA[nb] + lo1);
            gload16(pb0 + kb, sB[nb] + lo0);
            gload16(pb1 + kb, sB[nb] + lo1);
        }
        const unsigned short* cA = sA[cur];
        const unsigned short* cB = sB[cur];
        short8 af[4], bf[4];
        for (int i = 0; i < 4; i++)
            af[i] = *(const short8*)(cA + aoff + i * 16 * 32);
        for (int j = 0; j < 4; j++)
            bf[j] = *(const short8*)(cB + boff + j * 16 * 32);
        if (!swapAB) {
            for (int i = 0; i < 4; i++)
                for (int j = 0; j < 4; j++)
                    acc[i][j] = __builtin_amdgcn_mfma_f32_16x16x32_bf16(
                        af[i], bf[j], acc[i][j], 0, 0, 0);
        } else {
            for (int i = 0; i < 4; i++)
                for (int j = 0; j < 4; j++)
                    acc[i][j] = __builtin_amdgcn_mfma_f32_16x16x32_bf16(
                        bf[j], af[i], acc[i][j], 0, 0, 0);
        }
        if (it + 1 < NITER) {
            if (it + 2 < NITER) {
                asm volatile("s_waitcnt vmcnt(4)" ::: "memory");
            } else {
                asm volatile("s_waitcnt vmcnt(0)" ::: "memory");
            }
            phase_barrier();
        }
    }

    if (!swapAB) {
        const float QSCL = 0.18033688011112042f;  // 0.125 * log2(e)
        for (int i = 0; i < 4; i++)
            for (int j = 0; j < 4; j++)
                for (int r = 0; r < 4; r++) {
                    int m = blockM + wm * 64 + i * 16 + quad * 4 + r;
                    int n = blockN + wn * 64 + j * 16 + l16;
                    int part = n >> 10, c = n & 1023;
                    int h = c >> 6, d = c & 63;
                    int bb = m >> 11, t = m & 2047;
                    int bh = bb * NHEAD + h;
                    if (part == 0) {
                        dK[(((size_t)bh * T_SEQ + t) << 6) + d] = f2bf(acc[i][j][r]);
                    } else {
                        dQ[(((size_t)bh * T_SEQ + t) << 6) + d] =
                            f2bf(acc[i][j][r] * QSCL);
                    }
                }
    } else {
        for (int i = 0; i < 4; i++)
            for (int j = 0; j < 4; j++)
                for (int r = 0; r < 4; r++) {
                    int n = blockN + wn * 64 + j * 16 + quad * 4 + r;
                    int m = blockM + wm * 64 + i * 16 + l16;
                    int c = n & 1023;
                    int h = c >> 6, d = c & 63;
                    int bb = m >> 11, t = m & 2047;
                    int bh = bb * NHEAD + h;
                    dV[((size_t)bh * HDIM + d) * T_SEQ + t] = f2bf(acc[i][j][r]);
                }
    }
}

// ---------------- proj GEMM: 64x64 tile, BK=64, reg-prefetch --------------
// R0 proven version, FINAL.
__global__ __launch_bounds__(256) void gemm_proj(
    const unsigned short* __restrict__ A, const unsigned short* __restrict__ Bt,
    const float* __restrict__ bias, float* __restrict__ out) {
    const int K = 1024;
    const int NITER = K / 64;
    __shared__ unsigned short sA[2][64 * PROW];
    __shared__ unsigned short sB[2][64 * PROW];
    int tid = threadIdx.x, wave = tid >> 6, lane = tid & 63;
    int quad = lane >> 4, l16 = lane & 15;
    int wm = wave >> 1, wn = wave & 1;
    int blockM = blockIdx.y * 64, blockN = blockIdx.x * 64;

    int srow = tid >> 3;      // 0..31
    int sseg = tid & 7;       // 0..7
    const unsigned short* gA0 = A + (size_t)(blockM + srow) * K + sseg * 8;
    const unsigned short* gA1 = gA0 + (size_t)32 * K;
    const unsigned short* gB0 = Bt + (size_t)(blockN + srow) * K + sseg * 8;
    const unsigned short* gB1 = gB0 + (size_t)32 * K;
    int so0 = srow * PROW + sseg * 8;
    int so1 = (srow + 32) * PROW + sseg * 8;

    float4v acc[2][2] = {};
    uint4 ra0, ra1, rb0, rb1;

    ra0 = *(const uint4*)gA0; ra1 = *(const uint4*)gA1;
    rb0 = *(const uint4*)gB0; rb1 = *(const uint4*)gB1;
    *(uint4*)(sA[0] + so0) = ra0;
    *(uint4*)(sA[0] + so1) = ra1;
    *(uint4*)(sB[0] + so0) = rb0;
    *(uint4*)(sB[0] + so1) = rb1;

    int aoff = (wm * 32 + l16) * PROW + quad * 8;
    int boff = (wn * 32 + l16) * PROW + quad * 8;

    for (int it = 0; it < NITER; it++) {
        int cur = it & 1;
        __syncthreads();
        if (it + 1 < NITER) {
            int kb = (it + 1) * 64;
            ra0 = *(const uint4*)(gA0 + kb); ra1 = *(const uint4*)(gA1 + kb);
            rb0 = *(const uint4*)(gB0 + kb); rb1 = *(const uint4*)(gB1 + kb);
        }
        const unsigned short* cA = sA[cur];
        const unsigned short* cB = sB[cur];
        short8 af[2][2], bf[2][2];
        for (int i = 0; i < 2; i++)
            for (int k = 0; k < 2; k++)
                af[i][k] = *(const short8*)(cA + aoff + i * 16 * PROW + k * 32);
        for (int j = 0; j < 2; j++)
            for (int k = 0; k < 2; k++)
                bf[j][k] = *(const short8*)(cB + boff + j * 16 * PROW + k * 32);
        for (int i = 0; i < 2; i++)
            for (int j = 0; j < 2; j++) {
                acc[i][j] = __builtin_amdgcn_mfma_f32_16x16x32_bf16(
                    af[i][0], bf[j][0], acc[i][j], 0, 0, 0);
                acc[i][j] = __builtin_amdgcn_mfma_f32_16x16x32_bf16(
                    af[i][1], bf[j][1], acc[i][j], 0, 0, 0);
            }
        if (it + 1 < NITER) {
            int nxt = cur ^ 1;
            *(uint4*)(sA[nxt] + so0) = ra0;
            *(uint4*)(sA[nxt] + so1) = ra1;
            *(uint4*)(sB[nxt] + so0) = rb0;
            *(uint4*)(sB[nxt] + so1) = rb1;
        }
    }

    for (int i = 0; i < 2; i++)
        for (int j = 0; j < 2; j++)
            for (int r = 0; r < 4; r++) {
                int m = blockM + wm * 32 + i * 16 + quad * 4 + r;
                int n = blockN + wn * 32 + j * 16 + l16;
                out[(size_t)m * CDIM + n] = acc[i][j][r] + bias[n];
            }
}

// ---------------- flash attention v11: balanced xt + tree lsum ------------
// v9 plus:
//  (a) per-CU load balance: linear-round-robin gives CU c the y values
//      {y0, y0+8, y0+16, y0+24}. Old xt=31-y -> per-CU work 80-4*y0
//      (1.2x imbalance). New bijection (yq=y>>3, yg=y&7):
//      yq=0 -> 31-yg, 1 -> 16+yg, 2 -> 15-yg, 3 -> yg: every CU's four
//      blocks sum to exactly 66 tile-units; longest still dispatch first.
//  (b) lsum tree-reduce: pairwise (depth ~5) instead of 16 serial adds
//      (~64cy dependent chain per tile-step).
__global__ __launch_bounds__(256) void attn_fwd(
    const unsigned short* __restrict__ Qp, const unsigned short* __restrict__ Kp,
    const unsigned short* __restrict__ Vt, unsigned short* __restrict__ att) {
    __shared__ unsigned short sK[2][64 * 72];
    __shared__ unsigned short sV[2][64 * 72];
    int tid = threadIdx.x, wave = tid >> 6, lane = tid & 63;
    int quad = lane >> 4, l16 = lane & 15;
    int bh = blockIdx.x;
    int bb = bh >> 4, h = bh & 15;
    size_t baseQ = (size_t)bh * T_SEQ * HDIM;  // [t][d]
    size_t baseV = (size_t)bh * HDIM * T_SEQ;  // [d][t]
    int row4 = tid >> 2, seg = tid & 3;

    // balanced xt bijection (a)
    int yq = blockIdx.y >> 3, yg = blockIdx.y & 7;
    int xt;
    switch (yq) {
        case 0:  xt = 31 - yg; break;
        case 1:  xt = 16 + yg; break;
        case 2:  xt = 15 - yg; break;
        default: xt = yg;      break;
    }
    int qb = xt * 64;
    int qrow = qb + wave * 16 + l16;

    const unsigned short* qr = Qp + baseQ + (size_t)qrow * HDIM;
    short8 qf0 = *(const short8*)(qr + quad * 8);
    short8 qf1 = *(const short8*)(qr + 32 + quad * 8);

    float4v o[4] = {};
    float lsum = 0.f;
    int nt = xt + 1;

    uint4 ka, kb2, va, vb;
    {
        const unsigned short* gk = Kp + baseQ + (size_t)row4 * HDIM + seg * 16;
        const unsigned short* gv = Vt + baseV + (size_t)row4 * T_SEQ + seg * 16;
        ka = *(const uint4*)gk; kb2 = *(const uint4*)(gk + 8);
        va = *(const uint4*)gv; vb = *(const uint4*)(gv + 8);
    }
    *(uint4*)(sK[0] + row4 * 72 + seg * 16) = ka;
    *(uint4*)(sK[0] + row4 * 72 + seg * 16 + 8) = kb2;
    *(uint4*)(sV[0] + row4 * 72 + seg * 16) = va;
    *(uint4*)(sV[0] + row4 * 72 + seg * 16 + 8) = vb;

    const float4v NEG16 = {-16.f, -16.f, -16.f, -16.f};

    for (int t = 0; t < nt; t++) {
        int cur = t & 1;
        __syncthreads();
        if (t + 1 < nt) {
            const unsigned short* gk =
                Kp + baseQ + (size_t)((t + 1) * 64 + row4) * HDIM + seg * 16;
            const unsigned short* gv =
                Vt + baseV + (size_t)row4 * T_SEQ + (t + 1) * 64 + seg * 16;
            ka = *(const uint4*)gk; kb2 = *(const uint4*)(gk + 8);
            va = *(const uint4*)gv; vb = *(const uint4*)(gv + 8);
        }

        const unsigned short* cK = sK[cur];
        const unsigned short* cV = sV[cur];
        float4v s[4];
        __builtin_amdgcn_s_setprio(1);
        for (int sub = 0; sub < 4; sub++) {
            short8 kf0 = *(const short8*)(cK + (sub * 16 + l16) * 72 + quad * 8);
            short8 kf1 =
                *(const short8*)(cK + (sub * 16 + l16) * 72 + 32 + quad * 8);
            float4v z = NEG16;  // fixed-max -16 folded into C-init
            z = __builtin_amdgcn_mfma_f32_16x16x32_bf16(kf0, qf0, z, 0, 0, 0);
            z = __builtin_amdgcn_mfma_f32_16x16x32_bf16(kf1, qf1, z, 0, 0, 0);
            s[sub] = z;
        }
        __builtin_amdgcn_s_setprio(0);

        float e[16];
        bool need_mask = (t * 64 + 63) > (qb + wave * 16);  // wave-uniform
        if (need_mask) {
            int kgb = t * 64 + quad * 4;
            for (int sub = 0; sub < 4; sub++)
                for (int r = 0; r < 4; r++) {
                    float v = __builtin_amdgcn_exp2f(s[sub][r]);
                    v = (kgb + sub * 16 + r <= qrow) ? v : 0.0f;
                    e[sub * 4 + r] = v;
                }
        } else {
            for (int sub = 0; sub < 4; sub++)
                for (int r = 0; r < 4; r++)
                    e[sub * 4 + r] = __builtin_amdgcn_exp2f(s[sub][r]);
        }
        // tree-reduce (b): depth ~5 instead of 16 serial adds
        {
            float t0 = (e[0] + e[1]) + (e[2] + e[3]);
            float t1 = (e[4] + e[5]) + (e[6] + e[7]);
            float t2 = (e[8] + e[9]) + (e[10] + e[11]);
            float t3 = (e[12] + e[13]) + (e[14] + e[15]);
            lsum += (t0 + t1) + (t2 + t3);
        }

        __builtin_amdgcn_s_setprio(1);
        for (int sub = 0; sub < 4; sub++) {
            unsigned lo, hi;
            asm("v_cvt_pk_bf16_f32 %0, %1, %2"
                : "=v"(lo) : "v"(e[sub * 4 + 0]), "v"(e[sub * 4 + 1]));
            asm("v_cvt_pk_bf16_f32 %0, %1, %2"
                : "=v"(hi) : "v"(e[sub * 4 + 2]), "v"(e[sub * 4 + 3]));
            uint2 packed = {lo, hi};
            short4v pf = __builtin_bit_cast(short4v, packed);
            for (int dc = 0; dc < 4; dc++) {
                short4v vf = *(const short4v*)(
                    cV + (dc * 16 + l16) * 72 + sub * 16 + quad * 4);
                o[dc] = __builtin_amdgcn_mfma_f32_16x16x16bf16_1k(
                    vf, pf, o[dc], 0, 0, 0);
            }
        }
        __builtin_amdgcn_s_setprio(0);

        if (t + 1 < nt) {
            int nxt = cur ^ 1;
            *(uint4*)(sK[nxt] + row4 * 72 + seg * 16) = ka;
            *(uint4*)(sK[nxt] + row4 * 72 + seg * 16 + 8) = kb2;
            *(uint4*)(sV[nxt] + row4 * 72 + seg * 16) = va;
            *(uint4*)(sV[nxt] + row4 * 72 + seg * 16 + 8) = vb;
        }
    }

    lsum += __shfl_xor(lsum, 16);
    lsum += __shfl_xor(lsum, 32);
    float inv = 1.0f / lsum;

    __syncthreads();
    for (int dc = 0; dc < 4; dc++) {
        short4v ov;
        for (int r = 0; r < 4; r++) ov[r] = (short)f2bf(o[dc][r] * inv);
        *(short4v*)(sK[0] + wave * 1152 + l16 * 72 + dc * 16 + quad * 4) = ov;
    }
    __syncthreads();
    int orow = lane >> 2, oseg = lane & 3;
    uint4 a = *(const uint4*)(sK[0] + wave * 1152 + orow * 72 + oseg * 16);
    uint4 b = *(const uint4*)(sK[0] + wave * 1152 + orow * 72 + oseg * 16 + 8);
    unsigned short* dst = att +
        (size_t)(bb * T_SEQ + qb + wave * 16 + orow) * CDIM + h * HDIM +
        oseg * 16;
    *(uint4*)dst = a;
    *(uint4*)(dst + 8) = b;
}

// ---------------- launch ----------------
extern "C" void kernel_launch(void* const* d_in, const int* in_sizes, int n_in,
                              void* d_out, int out_size, void* d_ws, size_t ws_size,
                              hipStream_t stream) {
    const float* x      = (const float*)d_in[0];   // [2,2048,1024]
    const float* W_attn = (const float*)d_in[1];   // [1024,3072]
    const float* W_proj = (const float*)d_in[2];   // [1024,1024]
    const float* b_proj = (const float*)d_in[3];   // [1024]
    float* out = (float*)d_out;                    // [2,2048,1024]

    unsigned short* xb   = (unsigned short*)d_ws;          // 4096*1024
    unsigned short* WaT  = xb  + 4096 * 1024;              // 3072*1024 (transposed)
    unsigned short* WpT  = WaT + 3072 * 1024;              // 1024*1024 (transposed)
    unsigned short* Karr = WpT + 1024 * 1024;              // [B,H,T,64]
    unsigned short* Qarr = Karr + 2 * 16 * 2048 * 64;      // [B,H,T,64] pre-scaled
    unsigned short* Varr = Qarr + 2 * 16 * 2048 * 64;      // [B,H,64,T] transposed
    unsigned short* attb = Varr + 2 * 16 * 2048 * 64;      // 4096*1024

    preproc<<<8192, 256, 0, stream>>>(x, xb, W_attn, WaT, W_proj, WpT);
    gemm_qkv<<<dim3(24, 32), 256, 0, stream>>>(xb, WaT, Karr, Qarr, Varr);
    attn_fwd<<<dim3(32, 32), 256, 0, stream>>>(Qarr, Karr, Varr, attb);
    gemm_proj<<<dim3(16, 64), 256, 0, stream>>>(attb, WpT, b_proj, out);
}

// Round 13
// 187.853 us; speedup vs baseline: 1.0127x; 1.0127x over previous
//
#include <hip/hip_runtime.h>

typedef __attribute__((ext_vector_type(8))) short short8;
typedef __attribute__((ext_vector_type(4))) short short4v;
typedef __attribute__((ext_vector_type(4))) float float4v;

#define T_SEQ 2048
#define CDIM 1024
#define NHEAD 16
#define HDIM 64
#define PROW 72  // proj LDS row stride (shorts), BK=64 + pad

__device__ __forceinline__ unsigned short f2bf(float f) {
    unsigned u = __builtin_bit_cast(unsigned, f);
    u += 0x7FFF + ((u >> 16) & 1);
    return (unsigned short)(u >> 16);
}

// async global->LDS, 16B per lane. LDS dest wave-uniform base + lane*16B.
__device__ __forceinline__ void gload16(const unsigned short* g,
                                        unsigned short* l) {
    __builtin_amdgcn_global_load_lds(
        (const __attribute__((address_space(1))) unsigned int*)g,
        (__attribute__((address_space(3))) unsigned int*)l, 16, 0, 0);
}

// raw barrier WITHOUT the implicit vmcnt(0) drain of __syncthreads.
__device__ __forceinline__ void phase_barrier() {
    __builtin_amdgcn_sched_barrier(0);
    __builtin_amdgcn_s_barrier();
    __builtin_amdgcn_sched_barrier(0);
}

// ---------------- fused preprocessing: convert + 2 transposes -------------
__global__ __launch_bounds__(256) void preproc(
    const float* __restrict__ x, unsigned short* __restrict__ xb,
    const float* __restrict__ Wa, unsigned short* __restrict__ WaT,
    const float* __restrict__ Wp, unsigned short* __restrict__ WpT) {
    int bid = blockIdx.x, tid = threadIdx.x;
    if (bid < 4096) {
        int i = bid * 256 + tid;
        float4 v = ((const float4*)x)[i];
        ushort4 o;
        o.x = f2bf(v.x); o.y = f2bf(v.y); o.z = f2bf(v.z); o.w = f2bf(v.w);
        ((ushort4*)xb)[i] = o;
        return;
    }
    __shared__ float tile[32][33];
    const float* in;
    unsigned short* out;
    int N, b;
    if (bid < 4096 + 3072) {
        b = bid - 4096; in = Wa; out = WaT; N = 3072;
    } else {
        b = bid - 7168; in = Wp; out = WpT; N = 1024;
    }
    const int K = 1024;
    int kb = (b & 31) * 32, nb = (b >> 5) * 32;
    int tx = tid & 31, ty = tid >> 5;  // ty 0..7
    for (int r = 0; r < 4; r++)
        tile[ty + r * 8][tx] = in[(size_t)(kb + ty + r * 8) * N + nb + tx];
    __syncthreads();
    for (int r = 0; r < 4; r++)
        out[(size_t)(nb + ty + r * 8) * K + kb + tx] = f2bf(tile[tx][ty + r * 8]);
}

// ---------------- QKV GEMM: 128x128, BK=32, 3-buffer counted-vmcnt --------
// R6 proven FINAL (49.2-49.6us). gload_lds staging (no staging VALU),
// 3-deep buffer rotation, vmcnt(4) never drains in main loop; 768 blocks
// = 3/CU, default dispatch order (R11 XCD swizzle regressed: FETCH +36%).
// Closed avenues at this K=1024 shape: 8-phase 256^2 (R7, +20us),
// unroll-3 (R9, neutral), XCD swizzle (R11).
__global__ __launch_bounds__(256) void gemm_qkv(
    const unsigned short* __restrict__ A, const unsigned short* __restrict__ Bt,
    unsigned short* __restrict__ dK, unsigned short* __restrict__ dQ,
    unsigned short* __restrict__ dV) {
    const int K = 1024;
    const int NITER = K / 32;  // 32
    __shared__ unsigned short sA[3][128 * 32];
    __shared__ unsigned short sB[3][128 * 32];
    int tid = threadIdx.x, wave = tid >> 6, lane = tid & 63;
    int quad = lane >> 4, l16 = lane & 15;
    int wm = wave >> 1, wn = wave & 1;
    int blockM = blockIdx.y * 128, blockN = blockIdx.x * 128;
    bool swapAB = (blockN >= 2048);  // V part: produce C^T

    const unsigned short* gA = A + (size_t)blockM * K;
    const unsigned short* gB = Bt + (size_t)blockN * K;

    int srow = wave * 32 + (lane >> 2);
    int scol = (lane & 3) * 8;
    const unsigned short* pa0 = gA + (size_t)srow * K + scol;
    const unsigned short* pa1 = pa0 + (size_t)16 * K;
    const unsigned short* pb0 = gB + (size_t)srow * K + scol;
    const unsigned short* pb1 = pb0 + (size_t)16 * K;
    int lo0 = (wave * 32) * 32;
    int lo1 = (wave * 32 + 16) * 32;

    float4v acc[4][4] = {};
    int aoff = (wm * 64 + l16) * 32 + quad * 8;
    int boff = (wn * 64 + l16) * 32 + quad * 8;

    for (int t = 0; t < 2; t++) {
        int kb = t * 32;
        gload16(pa0 + kb, sA[t] + lo0);
        gload16(pa1 + kb, sA[t] + lo1);
        gload16(pb0 + kb, sB[t] + lo0);
        gload16(pb1 + kb, sB[t] + lo1);
    }
    asm volatile("s_waitcnt vmcnt(4)" ::: "memory");
    phase_barrier();

#pragma unroll
    for (int it = 0; it < NITER; it++) {
        int cur = it % 3;
        if (it + 2 < NITER) {
            int kb = (it + 2) * 32;
            int nb = (it + 2) % 3;
            gload16(pa0 + kb, sA[nb] + lo0);
            gload16(pa1 + kb, sA[nb] + lo1);
            gload16(pb0 + kb, sB[nb] + lo0);
            gload16(pb1 + kb, sB[nb] + lo1);
        }
        const unsigned short* cA = sA[cur];
        const unsigned short* cB = sB[cur];
        short8 af[4], bf[4];
        for (int i = 0; i < 4; i++)
            af[i] = *(const short8*)(cA + aoff + i * 16 * 32);
        for (int j = 0; j < 4; j++)
            bf[j] = *(const short8*)(cB + boff + j * 16 * 32);
        if (!swapAB) {
            for (int i = 0; i < 4; i++)
                for (int j = 0; j < 4; j++)
                    acc[i][j] = __builtin_amdgcn_mfma_f32_16x16x32_bf16(
                        af[i], bf[j], acc[i][j], 0, 0, 0);
        } else {
            for (int i = 0; i < 4; i++)
                for (int j = 0; j < 4; j++)
                    acc[i][j] = __builtin_amdgcn_mfma_f32_16x16x32_bf16(
                        bf[j], af[i], acc[i][j], 0, 0, 0);
        }
        if (it + 1 < NITER) {
            if (it + 2 < NITER) {
                asm volatile("s_waitcnt vmcnt(4)" ::: "memory");
            } else {
                asm volatile("s_waitcnt vmcnt(0)" ::: "memory");
            }
            phase_barrier();
        }
    }

    if (!swapAB) {
        const float QSCL = 0.18033688011112042f;  // 0.125 * log2(e)
        for (int i = 0; i < 4; i++)
            for (int j = 0; j < 4; j++)
                for (int r = 0; r < 4; r++) {
                    int m = blockM + wm * 64 + i * 16 + quad * 4 + r;
                    int n = blockN + wn * 64 + j * 16 + l16;
                    int part = n >> 10, c = n & 1023;
                    int h = c >> 6, d = c & 63;
                    int bb = m >> 11, t = m & 2047;
                    int bh = bb * NHEAD + h;
                    if (part == 0) {
                        dK[(((size_t)bh * T_SEQ + t) << 6) + d] = f2bf(acc[i][j][r]);
                    } else {
                        dQ[(((size_t)bh * T_SEQ + t) << 6) + d] =
                            f2bf(acc[i][j][r] * QSCL);
                    }
                }
    } else {
        for (int i = 0; i < 4; i++)
            for (int j = 0; j < 4; j++)
                for (int r = 0; r < 4; r++) {
                    int n = blockN + wn * 64 + j * 16 + quad * 4 + r;
                    int m = blockM + wm * 64 + i * 16 + l16;
                    int c = n & 1023;
                    int h = c >> 6, d = c & 63;
                    int bb = m >> 11, t = m & 2047;
                    int bh = bb * NHEAD + h;
                    dV[((size_t)bh * HDIM + d) * T_SEQ + t] = f2bf(acc[i][j][r]);
                }
    }
}

// ---------------- proj GEMM: 64x64 tile, BK=64, reg-prefetch --------------
// R0 proven FINAL. 1024 blocks = 4/CU; cross-block overlap at 4/CU beats
// every deeper-pipelined lower-occupancy variant at K=1024 (R5: 128^2
// 1/CU +11us; R10: 64x128 2/CU +4.5us).
__global__ __launch_bounds__(256) void gemm_proj(
    const unsigned short* __restrict__ A, const unsigned short* __restrict__ Bt,
    const float* __restrict__ bias, float* __restrict__ out) {
    const int K = 1024;
    const int NITER = K / 64;
    __shared__ unsigned short sA[2][64 * PROW];
    __shared__ unsigned short sB[2][64 * PROW];
    int tid = threadIdx.x, wave = tid >> 6, lane = tid & 63;
    int quad = lane >> 4, l16 = lane & 15;
    int wm = wave >> 1, wn = wave & 1;
    int blockM = blockIdx.y * 64, blockN = blockIdx.x * 64;

    int srow = tid >> 3;      // 0..31
    int sseg = tid & 7;       // 0..7
    const unsigned short* gA0 = A + (size_t)(blockM + srow) * K + sseg * 8;
    const unsigned short* gA1 = gA0 + (size_t)32 * K;
    const unsigned short* gB0 = Bt + (size_t)(blockN + srow) * K + sseg * 8;
    const unsigned short* gB1 = gB0 + (size_t)32 * K;
    int so0 = srow * PROW + sseg * 8;
    int so1 = (srow + 32) * PROW + sseg * 8;

    float4v acc[2][2] = {};
    uint4 ra0, ra1, rb0, rb1;

    ra0 = *(const uint4*)gA0; ra1 = *(const uint4*)gA1;
    rb0 = *(const uint4*)gB0; rb1 = *(const uint4*)gB1;
    *(uint4*)(sA[0] + so0) = ra0;
    *(uint4*)(sA[0] + so1) = ra1;
    *(uint4*)(sB[0] + so0) = rb0;
    *(uint4*)(sB[0] + so1) = rb1;

    int aoff = (wm * 32 + l16) * PROW + quad * 8;
    int boff = (wn * 32 + l16) * PROW + quad * 8;

    for (int it = 0; it < NITER; it++) {
        int cur = it & 1;
        __syncthreads();
        if (it + 1 < NITER) {
            int kb = (it + 1) * 64;
            ra0 = *(const uint4*)(gA0 + kb); ra1 = *(const uint4*)(gA1 + kb);
            rb0 = *(const uint4*)(gB0 + kb); rb1 = *(const uint4*)(gB1 + kb);
        }
        const unsigned short* cA = sA[cur];
        const unsigned short* cB = sB[cur];
        short8 af[2][2], bf[2][2];
        for (int i = 0; i < 2; i++)
            for (int k = 0; k < 2; k++)
                af[i][k] = *(const short8*)(cA + aoff + i * 16 * PROW + k * 32);
        for (int j = 0; j < 2; j++)
            for (int k = 0; k < 2; k++)
                bf[j][k] = *(const short8*)(cB + boff + j * 16 * PROW + k * 32);
        for (int i = 0; i < 2; i++)
            for (int j = 0; j < 2; j++) {
                acc[i][j] = __builtin_amdgcn_mfma_f32_16x16x32_bf16(
                    af[i][0], bf[j][0], acc[i][j], 0, 0, 0);
                acc[i][j] = __builtin_amdgcn_mfma_f32_16x16x32_bf16(
                    af[i][1], bf[j][1], acc[i][j], 0, 0, 0);
            }
        if (it + 1 < NITER) {
            int nxt = cur ^ 1;
            *(uint4*)(sA[nxt] + so0) = ra0;
            *(uint4*)(sA[nxt] + so1) = ra1;
            *(uint4*)(sB[nxt] + so0) = rb0;
            *(uint4*)(sB[nxt] + so1) = rb1;
        }
    }

    for (int i = 0; i < 2; i++)
        for (int j = 0; j < 2; j++)
            for (int r = 0; r < 4; r++) {
                int m = blockM + wm * 32 + i * 16 + quad * 4 + r;
                int n = blockN + wn * 32 + j * 16 + l16;
                out[(size_t)m * CDIM + n] = acc[i][j][r] + bias[n];
            }
}

// ---------------- flash attention v9: FINAL ------------------------------
// R6 proven version. xt = 31 - y IS the LPT greedy schedule (longest
// blocks dispatch first; greedy CU assignment self-balances) -- R12's
// "balanced" remap broke monotonicity and regressed +3.5us. Serial lsum
// restored with it (bundled in R12; unproven alone).
// Techniques: fixed-max -16 in MFMA C-init; wave-uniform hoisted causal
// mask; raw v_exp_f32; v_cvt_pk_bf16_f32 packing; T5 setprio on MFMA
// clusters; reg-prefetch dbuf K/V staging; (32 bh, 32 xt) grid = 4
// blocks/CU cross-block overlap.
__global__ __launch_bounds__(256) void attn_fwd(
    const unsigned short* __restrict__ Qp, const unsigned short* __restrict__ Kp,
    const unsigned short* __restrict__ Vt, unsigned short* __restrict__ att) {
    __shared__ unsigned short sK[2][64 * 72];
    __shared__ unsigned short sV[2][64 * 72];
    int tid = threadIdx.x, wave = tid >> 6, lane = tid & 63;
    int quad = lane >> 4, l16 = lane & 15;
    int bh = blockIdx.x;
    int bb = bh >> 4, h = bh & 15;
    size_t baseQ = (size_t)bh * T_SEQ * HDIM;  // [t][d]
    size_t baseV = (size_t)bh * HDIM * T_SEQ;  // [d][t]
    int row4 = tid >> 2, seg = tid & 3;

    int xt = 31 - blockIdx.y;
    int qb = xt * 64;
    int qrow = qb + wave * 16 + l16;

    const unsigned short* qr = Qp + baseQ + (size_t)qrow * HDIM;
    short8 qf0 = *(const short8*)(qr + quad * 8);
    short8 qf1 = *(const short8*)(qr + 32 + quad * 8);

    float4v o[4] = {};
    float lsum = 0.f;
    int nt = xt + 1;

    uint4 ka, kb2, va, vb;
    {
        const unsigned short* gk = Kp + baseQ + (size_t)row4 * HDIM + seg * 16;
        const unsigned short* gv = Vt + baseV + (size_t)row4 * T_SEQ + seg * 16;
        ka = *(const uint4*)gk; kb2 = *(const uint4*)(gk + 8);
        va = *(const uint4*)gv; vb = *(const uint4*)(gv + 8);
    }
    *(uint4*)(sK[0] + row4 * 72 + seg * 16) = ka;
    *(uint4*)(sK[0] + row4 * 72 + seg * 16 + 8) = kb2;
    *(uint4*)(sV[0] + row4 * 72 + seg * 16) = va;
    *(uint4*)(sV[0] + row4 * 72 + seg * 16 + 8) = vb;

    const float4v NEG16 = {-16.f, -16.f, -16.f, -16.f};

    for (int t = 0; t < nt; t++) {
        int cur = t & 1;
        __syncthreads();
        if (t + 1 < nt) {
            const unsigned short* gk =
                Kp + baseQ + (size_t)((t + 1) * 64 + row4) * HDIM + seg * 16;
            const unsigned short* gv =
                Vt + baseV + (size_t)row4 * T_SEQ + (t + 1) * 64 + seg * 16;
            ka = *(const uint4*)gk; kb2 = *(const uint4*)(gk + 8);
            va = *(const uint4*)gv; vb = *(const uint4*)(gv + 8);
        }

        const unsigned short* cK = sK[cur];
        const unsigned short* cV = sV[cur];
        float4v s[4];
        __builtin_amdgcn_s_setprio(1);
        for (int sub = 0; sub < 4; sub++) {
            short8 kf0 = *(const short8*)(cK + (sub * 16 + l16) * 72 + quad * 8);
            short8 kf1 =
                *(const short8*)(cK + (sub * 16 + l16) * 72 + 32 + quad * 8);
            float4v z = NEG16;  // fixed-max -16 folded into C-init
            z = __builtin_amdgcn_mfma_f32_16x16x32_bf16(kf0, qf0, z, 0, 0, 0);
            z = __builtin_amdgcn_mfma_f32_16x16x32_bf16(kf1, qf1, z, 0, 0, 0);
            s[sub] = z;
        }
        __builtin_amdgcn_s_setprio(0);

        float e[16];
        bool need_mask = (t * 64 + 63) > (qb + wave * 16);  // wave-uniform
        if (need_mask) {
            int kgb = t * 64 + quad * 4;
            for (int sub = 0; sub < 4; sub++)
                for (int r = 0; r < 4; r++) {
                    float v = __builtin_amdgcn_exp2f(s[sub][r]);
                    v = (kgb + sub * 16 + r <= qrow) ? v : 0.0f;
                    e[sub * 4 + r] = v;
                    lsum += v;
                }
        } else {
            for (int sub = 0; sub < 4; sub++)
                for (int r = 0; r < 4; r++) {
                    float v = __builtin_amdgcn_exp2f(s[sub][r]);
                    e[sub * 4 + r] = v;
                    lsum += v;
                }
        }

        __builtin_amdgcn_s_setprio(1);
        for (int sub = 0; sub < 4; sub++) {
            unsigned lo, hi;
            asm("v_cvt_pk_bf16_f32 %0, %1, %2"
                : "=v"(lo) : "v"(e[sub * 4 + 0]), "v"(e[sub * 4 + 1]));
            asm("v_cvt_pk_bf16_f32 %0, %1, %2"
                : "=v"(hi) : "v"(e[sub * 4 + 2]), "v"(e[sub * 4 + 3]));
            uint2 packed = {lo, hi};
            short4v pf = __builtin_bit_cast(short4v, packed);
            for (int dc = 0; dc < 4; dc++) {
                short4v vf = *(const short4v*)(
                    cV + (dc * 16 + l16) * 72 + sub * 16 + quad * 4);
                o[dc] = __builtin_amdgcn_mfma_f32_16x16x16bf16_1k(
                    vf, pf, o[dc], 0, 0, 0);
            }
        }
        __builtin_amdgcn_s_setprio(0);

        if (t + 1 < nt) {
            int nxt = cur ^ 1;
            *(uint4*)(sK[nxt] + row4 * 72 + seg * 16) = ka;
            *(uint4*)(sK[nxt] + row4 * 72 + seg * 16 + 8) = kb2;
            *(uint4*)(sV[nxt] + row4 * 72 + seg * 16) = va;
            *(uint4*)(sV[nxt] + row4 * 72 + seg * 16 + 8) = vb;
        }
    }

    lsum += __shfl_xor(lsum, 16);
    lsum += __shfl_xor(lsum, 32);
    float inv = 1.0f / lsum;

    __syncthreads();
    for (int dc = 0; dc < 4; dc++) {
        short4v ov;
        for (int r = 0; r < 4; r++) ov[r] = (short)f2bf(o[dc][r] * inv);
        *(short4v*)(sK[0] + wave * 1152 + l16 * 72 + dc * 16 + quad * 4) = ov;
    }
    __syncthreads();
    int orow = lane >> 2, oseg = lane & 3;
    uint4 a = *(const uint4*)(sK[0] + wave * 1152 + orow * 72 + oseg * 16);
    uint4 b = *(const uint4*)(sK[0] + wave * 1152 + orow * 72 + oseg * 16 + 8);
    unsigned short* dst = att +
        (size_t)(bb * T_SEQ + qb + wave * 16 + orow) * CDIM + h * HDIM +
        oseg * 16;
    *(uint4*)dst = a;
    *(uint4*)(dst + 8) = b;
}

// ---------------- launch ----------------
extern "C" void kernel_launch(void* const* d_in, const int* in_sizes, int n_in,
                              void* d_out, int out_size, void* d_ws, size_t ws_size,
                              hipStream_t stream) {
    const float* x      = (const float*)d_in[0];   // [2,2048,1024]
    const float* W_attn = (const float*)d_in[1];   // [1024,3072]
    const float* W_proj = (const float*)d_in[2];   // [1024,1024]
    const float* b_proj = (const float*)d_in[3];   // [1024]
    float* out = (float*)d_out;                    // [2,2048,1024]

    unsigned short* xb   = (unsigned short*)d_ws;          // 4096*1024
    unsigned short* WaT  = xb  + 4096 * 1024;              // 3072*1024 (transposed)
    unsigned short* WpT  = WaT + 3072 * 1024;              // 1024*1024 (transposed)
    unsigned short* Karr = WpT + 1024 * 1024;              // [B,H,T,64]
    unsigned short* Qarr = Karr + 2 * 16 * 2048 * 64;      // [B,H,T,64] pre-scaled
    unsigned short* Varr = Qarr + 2 * 16 * 2048 * 64;      // [B,H,64,T] transposed
    unsigned short* attb = Varr + 2 * 16 * 2048 * 64;      // 4096*1024

    preproc<<<8192, 256, 0, stream>>>(x, xb, W_attn, WaT, W_proj, WpT);
    gemm_qkv<<<dim3(24, 32), 256, 0, stream>>>(xb, WaT, Karr, Qarr, Varr);
    attn_fwd<<<dim3(32, 32), 256, 0, stream>>>(Qarr, Karr, Varr, attb);
    gemm_proj<<<dim3(16, 64), 256, 0, stream>>>(attb, WpT, b_proj, out);
}

// Round 14
// 180.375 us; speedup vs baseline: 1.0546x; 1.0415x over previous
//
#include <hip/hip_runtime.h>

typedef __attribute__((ext_vector_type(8))) short short8;
typedef __attribute__((ext_vector_type(4))) short short4v;
typedef __attribute__((ext_vector_type(4))) float float4v;

#define T_SEQ 2048
#define CDIM 1024
#define NHEAD 16
#define HDIM 64
#define PROW 72  // proj LDS row stride (shorts), BK=64 + pad

__device__ __forceinline__ unsigned short f2bf(float f) {
    unsigned u = __builtin_bit_cast(unsigned, f);
    u += 0x7FFF + ((u >> 16) & 1);
    return (unsigned short)(u >> 16);
}

// async global->LDS, 16B per lane. LDS dest wave-uniform base + lane*16B.
__device__ __forceinline__ void gload16(const unsigned short* g,
                                        unsigned short* l) {
    __builtin_amdgcn_global_load_lds(
        (const __attribute__((address_space(1))) unsigned int*)g,
        (__attribute__((address_space(3))) unsigned int*)l, 16, 0, 0);
}

// raw barrier WITHOUT the implicit vmcnt(0) drain of __syncthreads.
__device__ __forceinline__ void phase_barrier() {
    __builtin_amdgcn_sched_barrier(0);
    __builtin_amdgcn_s_barrier();
    __builtin_amdgcn_sched_barrier(0);
}

// ---------------- fused preprocessing: convert + 2 transposes -------------
__global__ __launch_bounds__(256) void preproc(
    const float* __restrict__ x, unsigned short* __restrict__ xb,
    const float* __restrict__ Wa, unsigned short* __restrict__ WaT,
    const float* __restrict__ Wp, unsigned short* __restrict__ WpT) {
    int bid = blockIdx.x, tid = threadIdx.x;
    if (bid < 4096) {
        int i = bid * 256 + tid;
        float4 v = ((const float4*)x)[i];
        ushort4 o;
        o.x = f2bf(v.x); o.y = f2bf(v.y); o.z = f2bf(v.z); o.w = f2bf(v.w);
        ((ushort4*)xb)[i] = o;
        return;
    }
    __shared__ float tile[32][33];
    const float* in;
    unsigned short* out;
    int N, b;
    if (bid < 4096 + 3072) {
        b = bid - 4096; in = Wa; out = WaT; N = 3072;
    } else {
        b = bid - 7168; in = Wp; out = WpT; N = 1024;
    }
    const int K = 1024;
    int kb = (b & 31) * 32, nb = (b >> 5) * 32;
    int tx = tid & 31, ty = tid >> 5;  // ty 0..7
    for (int r = 0; r < 4; r++)
        tile[ty + r * 8][tx] = in[(size_t)(kb + ty + r * 8) * N + nb + tx];
    __syncthreads();
    for (int r = 0; r < 4; r++)
        out[(size_t)(nb + ty + r * 8) * K + kb + tx] = f2bf(tile[tx][ty + r * 8]);
}

// ---------------- QKV GEMM: 128x128, BK=32, 3-buffer, 8 waves -------------
// R14: same proven 3-buffer counted-vmcnt sync structure as R6 (barriers/
// iter identical), but 512 threads: work per wave halves (acc[2][4],
// 8 MFMA/iter, 2 gloads/tile/wave -> per-wave vmcnt(2)), LDS unchanged
// (48KB -> 3 blocks/CU) => 24 waves/CU = 6/SIMD, 2x TLP vs R6's 3/SIMD.
// Theory: Occupancy 15% / MfmaUtil 19% / all-pipes-idle = stalls with
// too little TLP cover; doubling wave count hides the same stalls.
__global__ __launch_bounds__(512) void gemm_qkv(
    const unsigned short* __restrict__ A, const unsigned short* __restrict__ Bt,
    unsigned short* __restrict__ dK, unsigned short* __restrict__ dQ,
    unsigned short* __restrict__ dV) {
    const int K = 1024;
    const int NITER = K / 32;  // 32
    __shared__ unsigned short sA[3][128 * 32];
    __shared__ unsigned short sB[3][128 * 32];
    int tid = threadIdx.x, wave = tid >> 6, lane = tid & 63;
    int quad = lane >> 4, l16 = lane & 15;
    int wm = wave >> 1, wn = wave & 1;  // 4M x 2N wave grid
    int blockM = blockIdx.y * 128, blockN = blockIdx.x * 128;
    bool swapAB = (blockN >= 2048);  // V part: produce C^T

    const unsigned short* gA = A + (size_t)blockM * K;
    const unsigned short* gB = Bt + (size_t)blockN * K;

    // staging: wave w covers rows [w*16, w*16+16) of A and of B, one
    // gload16 each (64 lanes x 16B = 16 rows x 64B).
    int srow = wave * 16 + (lane >> 2);
    int scol = (lane & 3) * 8;
    const unsigned short* pa = gA + (size_t)srow * K + scol;
    const unsigned short* pb = gB + (size_t)srow * K + scol;
    int lo = (wave * 16) * 32;  // wave-uniform LDS offset (shorts)

    float4v acc[2][4] = {};
    int aoff = (wm * 32 + l16) * 32 + quad * 8;
    int boff = (wn * 64 + l16) * 32 + quad * 8;

    // prologue: stage tiles 0 and 1 (2 loads each per wave)
    for (int t = 0; t < 2; t++) {
        int kb = t * 32;
        gload16(pa + kb, sA[t] + lo);
        gload16(pb + kb, sB[t] + lo);
    }
    asm volatile("s_waitcnt vmcnt(2)" ::: "memory");  // tile 0 landed
    phase_barrier();

#pragma unroll
    for (int it = 0; it < NITER; it++) {
        int cur = it % 3;
        if (it + 2 < NITER) {
            int kb = (it + 2) * 32;
            int nb = (it + 2) % 3;
            gload16(pa + kb, sA[nb] + lo);
            gload16(pb + kb, sB[nb] + lo);
        }
        const unsigned short* cA = sA[cur];
        const unsigned short* cB = sB[cur];
        short8 af[2], bf[4];
        for (int i = 0; i < 2; i++)
            af[i] = *(const short8*)(cA + aoff + i * 16 * 32);
        for (int j = 0; j < 4; j++)
            bf[j] = *(const short8*)(cB + boff + j * 16 * 32);
        if (!swapAB) {
            for (int i = 0; i < 2; i++)
                for (int j = 0; j < 4; j++)
                    acc[i][j] = __builtin_amdgcn_mfma_f32_16x16x32_bf16(
                        af[i], bf[j], acc[i][j], 0, 0, 0);
        } else {
            for (int i = 0; i < 2; i++)
                for (int j = 0; j < 4; j++)
                    acc[i][j] = __builtin_amdgcn_mfma_f32_16x16x32_bf16(
                        bf[j], af[i], acc[i][j], 0, 0, 0);
        }
        if (it + 1 < NITER) {
            if (it + 2 < NITER) {
                // tile it+1 (2 loads) landed; it+2's 2 stay in flight
                asm volatile("s_waitcnt vmcnt(2)" ::: "memory");
            } else {
                asm volatile("s_waitcnt vmcnt(0)" ::: "memory");
            }
            phase_barrier();
        }
    }

    if (!swapAB) {
        const float QSCL = 0.18033688011112042f;  // 0.125 * log2(e)
        for (int i = 0; i < 2; i++)
            for (int j = 0; j < 4; j++)
                for (int r = 0; r < 4; r++) {
                    int m = blockM + wm * 32 + i * 16 + quad * 4 + r;
                    int n = blockN + wn * 64 + j * 16 + l16;
                    int part = n >> 10, c = n & 1023;
                    int h = c >> 6, d = c & 63;
                    int bb = m >> 11, t = m & 2047;
                    int bh = bb * NHEAD + h;
                    if (part == 0) {
                        dK[(((size_t)bh * T_SEQ + t) << 6) + d] = f2bf(acc[i][j][r]);
                    } else {
                        dQ[(((size_t)bh * T_SEQ + t) << 6) + d] =
                            f2bf(acc[i][j][r] * QSCL);
                    }
                }
    } else {
        for (int i = 0; i < 2; i++)
            for (int j = 0; j < 4; j++)
                for (int r = 0; r < 4; r++) {
                    int n = blockN + wn * 64 + j * 16 + quad * 4 + r;
                    int m = blockM + wm * 32 + i * 16 + l16;
                    int c = n & 1023;
                    int h = c >> 6, d = c & 63;
                    int bb = m >> 11, t = m & 2047;
                    int bh = bb * NHEAD + h;
                    dV[((size_t)bh * HDIM + d) * T_SEQ + t] = f2bf(acc[i][j][r]);
                }
    }
}

// ---------------- proj GEMM: 64x64 tile, BK=64, reg-prefetch --------------
// R0 proven FINAL (unchanged).
__global__ __launch_bounds__(256) void gemm_proj(
    const unsigned short* __restrict__ A, const unsigned short* __restrict__ Bt,
    const float* __restrict__ bias, float* __restrict__ out) {
    const int K = 1024;
    const int NITER = K / 64;
    __shared__ unsigned short sA[2][64 * PROW];
    __shared__ unsigned short sB[2][64 * PROW];
    int tid = threadIdx.x, wave = tid >> 6, lane = tid & 63;
    int quad = lane >> 4, l16 = lane & 15;
    int wm = wave >> 1, wn = wave & 1;
    int blockM = blockIdx.y * 64, blockN = blockIdx.x * 64;

    int srow = tid >> 3;      // 0..31
    int sseg = tid & 7;       // 0..7
    const unsigned short* gA0 = A + (size_t)(blockM + srow) * K + sseg * 8;
    const unsigned short* gA1 = gA0 + (size_t)32 * K;
    const unsigned short* gB0 = Bt + (size_t)(blockN + srow) * K + sseg * 8;
    const unsigned short* gB1 = gB0 + (size_t)32 * K;
    int so0 = srow * PROW + sseg * 8;
    int so1 = (srow + 32) * PROW + sseg * 8;

    float4v acc[2][2] = {};
    uint4 ra0, ra1, rb0, rb1;

    ra0 = *(const uint4*)gA0; ra1 = *(const uint4*)gA1;
    rb0 = *(const uint4*)gB0; rb1 = *(const uint4*)gB1;
    *(uint4*)(sA[0] + so0) = ra0;
    *(uint4*)(sA[0] + so1) = ra1;
    *(uint4*)(sB[0] + so0) = rb0;
    *(uint4*)(sB[0] + so1) = rb1;

    int aoff = (wm * 32 + l16) * PROW + quad * 8;
    int boff = (wn * 32 + l16) * PROW + quad * 8;

    for (int it = 0; it < NITER; it++) {
        int cur = it & 1;
        __syncthreads();
        if (it + 1 < NITER) {
            int kb = (it + 1) * 64;
            ra0 = *(const uint4*)(gA0 + kb); ra1 = *(const uint4*)(gA1 + kb);
            rb0 = *(const uint4*)(gB0 + kb); rb1 = *(const uint4*)(gB1 + kb);
        }
        const unsigned short* cA = sA[cur];
        const unsigned short* cB = sB[cur];
        short8 af[2][2], bf[2][2];
        for (int i = 0; i < 2; i++)
            for (int k = 0; k < 2; k++)
                af[i][k] = *(const short8*)(cA + aoff + i * 16 * PROW + k * 32);
        for (int j = 0; j < 2; j++)
            for (int k = 0; k < 2; k++)
                bf[j][k] = *(const short8*)(cB + boff + j * 16 * PROW + k * 32);
        for (int i = 0; i < 2; i++)
            for (int j = 0; j < 2; j++) {
                acc[i][j] = __builtin_amdgcn_mfma_f32_16x16x32_bf16(
                    af[i][0], bf[j][0], acc[i][j], 0, 0, 0);
                acc[i][j] = __builtin_amdgcn_mfma_f32_16x16x32_bf16(
                    af[i][1], bf[j][1], acc[i][j], 0, 0, 0);
            }
        if (it + 1 < NITER) {
            int nxt = cur ^ 1;
            *(uint4*)(sA[nxt] + so0) = ra0;
            *(uint4*)(sA[nxt] + so1) = ra1;
            *(uint4*)(sB[nxt] + so0) = rb0;
            *(uint4*)(sB[nxt] + so1) = rb1;
        }
    }

    for (int i = 0; i < 2; i++)
        for (int j = 0; j < 2; j++)
            for (int r = 0; r < 4; r++) {
                int m = blockM + wm * 32 + i * 16 + quad * 4 + r;
                int n = blockN + wn * 32 + j * 16 + l16;
                out[(size_t)m * CDIM + n] = acc[i][j][r] + bias[n];
            }
}

// ---------------- flash attention v9: FINAL ------------------------------
// R6 proven version (unchanged; xt=31-y is the LPT schedule).
__global__ __launch_bounds__(256) void attn_fwd(
    const unsigned short* __restrict__ Qp, const unsigned short* __restrict__ Kp,
    const unsigned short* __restrict__ Vt, unsigned short* __restrict__ att) {
    __shared__ unsigned short sK[2][64 * 72];
    __shared__ unsigned short sV[2][64 * 72];
    int tid = threadIdx.x, wave = tid >> 6, lane = tid & 63;
    int quad = lane >> 4, l16 = lane & 15;
    int bh = blockIdx.x;
    int bb = bh >> 4, h = bh & 15;
    size_t baseQ = (size_t)bh * T_SEQ * HDIM;  // [t][d]
    size_t baseV = (size_t)bh * HDIM * T_SEQ;  // [d][t]
    int row4 = tid >> 2, seg = tid & 3;

    int xt = 31 - blockIdx.y;
    int qb = xt * 64;
    int qrow = qb + wave * 16 + l16;

    const unsigned short* qr = Qp + baseQ + (size_t)qrow * HDIM;
    short8 qf0 = *(const short8*)(qr + quad * 8);
    short8 qf1 = *(const short8*)(qr + 32 + quad * 8);

    float4v o[4] = {};
    float lsum = 0.f;
    int nt = xt + 1;

    uint4 ka, kb2, va, vb;
    {
        const unsigned short* gk = Kp + baseQ + (size_t)row4 * HDIM + seg * 16;
        const unsigned short* gv = Vt + baseV + (size_t)row4 * T_SEQ + seg * 16;
        ka = *(const uint4*)gk; kb2 = *(const uint4*)(gk + 8);
        va = *(const uint4*)gv; vb = *(const uint4*)(gv + 8);
    }
    *(uint4*)(sK[0] + row4 * 72 + seg * 16) = ka;
    *(uint4*)(sK[0] + row4 * 72 + seg * 16 + 8) = kb2;
    *(uint4*)(sV[0] + row4 * 72 + seg * 16) = va;
    *(uint4*)(sV[0] + row4 * 72 + seg * 16 + 8) = vb;

    const float4v NEG16 = {-16.f, -16.f, -16.f, -16.f};

    for (int t = 0; t < nt; t++) {
        int cur = t & 1;
        __syncthreads();
        if (t + 1 < nt) {
            const unsigned short* gk =
                Kp + baseQ + (size_t)((t + 1) * 64 + row4) * HDIM + seg * 16;
            const unsigned short* gv =
                Vt + baseV + (size_t)row4 * T_SEQ + (t + 1) * 64 + seg * 16;
            ka = *(const uint4*)gk; kb2 = *(const uint4*)(gk + 8);
            va = *(const uint4*)gv; vb = *(const uint4*)(gv + 8);
        }

        const unsigned short* cK = sK[cur];
        const unsigned short* cV = sV[cur];
        float4v s[4];
        __builtin_amdgcn_s_setprio(1);
        for (int sub = 0; sub < 4; sub++) {
            short8 kf0 = *(const short8*)(cK + (sub * 16 + l16) * 72 + quad * 8);
            short8 kf1 =
                *(const short8*)(cK + (sub * 16 + l16) * 72 + 32 + quad * 8);
            float4v z = NEG16;  // fixed-max -16 folded into C-init
            z = __builtin_amdgcn_mfma_f32_16x16x32_bf16(kf0, qf0, z, 0, 0, 0);
            z = __builtin_amdgcn_mfma_f32_16x16x32_bf16(kf1, qf1, z, 0, 0, 0);
            s[sub] = z;
        }
        __builtin_amdgcn_s_setprio(0);

        float e[16];
        bool need_mask = (t * 64 + 63) > (qb + wave * 16);  // wave-uniform
        if (need_mask) {
            int kgb = t * 64 + quad * 4;
            for (int sub = 0; sub < 4; sub++)
                for (int r = 0; r < 4; r++) {
                    float v = __builtin_amdgcn_exp2f(s[sub][r]);
                    v = (kgb + sub * 16 + r <= qrow) ? v : 0.0f;
                    e[sub * 4 + r] = v;
                    lsum += v;
                }
        } else {
            for (int sub = 0; sub < 4; sub++)
                for (int r = 0; r < 4; r++) {
                    float v = __builtin_amdgcn_exp2f(s[sub][r]);
                    e[sub * 4 + r] = v;
                    lsum += v;
                }
        }

        __builtin_amdgcn_s_setprio(1);
        for (int sub = 0; sub < 4; sub++) {
            unsigned lo, hi;
            asm("v_cvt_pk_bf16_f32 %0, %1, %2"
                : "=v"(lo) : "v"(e[sub * 4 + 0]), "v"(e[sub * 4 + 1]));
            asm("v_cvt_pk_bf16_f32 %0, %1, %2"
                : "=v"(hi) : "v"(e[sub * 4 + 2]), "v"(e[sub * 4 + 3]));
            uint2 packed = {lo, hi};
            short4v pf = __builtin_bit_cast(short4v, packed);
            for (int dc = 0; dc < 4; dc++) {
                short4v vf = *(const short4v*)(
                    cV + (dc * 16 + l16) * 72 + sub * 16 + quad * 4);
                o[dc] = __builtin_amdgcn_mfma_f32_16x16x16bf16_1k(
                    vf, pf, o[dc], 0, 0, 0);
            }
        }
        __builtin_amdgcn_s_setprio(0);

        if (t + 1 < nt) {
            int nxt = cur ^ 1;
            *(uint4*)(sK[nxt] + row4 * 72 + seg * 16) = ka;
            *(uint4*)(sK[nxt] + row4 * 72 + seg * 16 + 8) = kb2;
            *(uint4*)(sV[nxt] + row4 * 72 + seg * 16) = va;
            *(uint4*)(sV[nxt] + row4 * 72 + seg * 16 + 8) = vb;
        }
    }

    lsum += __shfl_xor(lsum, 16);
    lsum += __shfl_xor(lsum, 32);
    float inv = 1.0f / lsum;

    __syncthreads();
    for (int dc = 0; dc < 4; dc++) {
        short4v ov;
        for (int r = 0; r < 4; r++) ov[r] = (short)f2bf(o[dc][r] * inv);
        *(short4v*)(sK[0] + wave * 1152 + l16 * 72 + dc * 16 + quad * 4) = ov;
    }
    __syncthreads();
    int orow = lane >> 2, oseg = lane & 3;
    uint4 a = *(const uint4*)(sK[0] + wave * 1152 + orow * 72 + oseg * 16);
    uint4 b = *(const uint4*)(sK[0] + wave * 1152 + orow * 72 + oseg * 16 + 8);
    unsigned short* dst = att +
        (size_t)(bb * T_SEQ + qb + wave * 16 + orow) * CDIM + h * HDIM +
        oseg * 16;
    *(uint4*)dst = a;
    *(uint4*)(dst + 8) = b;
}

// ---------------- launch ----------------
extern "C" void kernel_launch(void* const* d_in, const int* in_sizes, int n_in,
                              void* d_out, int out_size, void* d_ws, size_t ws_size,
                              hipStream_t stream) {
    const float* x      = (const float*)d_in[0];   // [2,2048,1024]
    const float* W_attn = (const float*)d_in[1];   // [1024,3072]
    const float* W_proj = (const float*)d_in[2];   // [1024,1024]
    const float* b_proj = (const float*)d_in[3];   // [1024]
    float* out = (float*)d_out;                    // [2,2048,1024]

    unsigned short* xb   = (unsigned short*)d_ws;          // 4096*1024
    unsigned short* WaT  = xb  + 4096 * 1024;              // 3072*1024 (transposed)
    unsigned short* WpT  = WaT + 3072 * 1024;              // 1024*1024 (transposed)
    unsigned short* Karr = WpT + 1024 * 1024;              // [B,H,T,64]
    unsigned short* Qarr = Karr + 2 * 16 * 2048 * 64;      // [B,H,T,64] pre-scaled
    unsigned short* Varr = Qarr + 2 * 16 * 2048 * 64;      // [B,H,64,T] transposed
    unsigned short* attb = Varr + 2 * 16 * 2048 * 64;      // 4096*1024

    preproc<<<8192, 256, 0, stream>>>(x, xb, W_attn, WaT, W_proj, WpT);
    gemm_qkv<<<dim3(24, 32), 512, 0, stream>>>(xb, WaT, Karr, Qarr, Varr);
    attn_fwd<<<dim3(32, 32), 256, 0, stream>>>(Qarr, Karr, Varr, attb);
    gemm_proj<<<dim3(16, 64), 256, 0, stream>>>(attb, WpT, b_proj, out);
}

// Round 15
// 175.392 us; speedup vs baseline: 1.0846x; 1.0284x over previous
//
#include <hip/hip_runtime.h>

typedef __attribute__((ext_vector_type(8))) short short8;
typedef __attribute__((ext_vector_type(4))) short short4v;
typedef __attribute__((ext_vector_type(4))) float float4v;

#define T_SEQ 2048
#define CDIM 1024
#define NHEAD 16
#define HDIM 64
#define PROW 72  // proj LDS row stride (shorts), BK=64 + pad

__device__ __forceinline__ unsigned short f2bf(float f) {
    unsigned u = __builtin_bit_cast(unsigned, f);
    u += 0x7FFF + ((u >> 16) & 1);
    return (unsigned short)(u >> 16);
}

// async global->LDS, 16B per lane. LDS dest wave-uniform base + lane*16B.
__device__ __forceinline__ void gload16(const unsigned short* g,
                                        unsigned short* l) {
    __builtin_amdgcn_global_load_lds(
        (const __attribute__((address_space(1))) unsigned int*)g,
        (__attribute__((address_space(3))) unsigned int*)l, 16, 0, 0);
}

// raw barrier WITHOUT the implicit vmcnt(0) drain of __syncthreads.
__device__ __forceinline__ void phase_barrier() {
    __builtin_amdgcn_sched_barrier(0);
    __builtin_amdgcn_s_barrier();
    __builtin_amdgcn_sched_barrier(0);
}

// ---------------- fused preprocessing: convert + 2 transposes -------------
__global__ __launch_bounds__(256) void preproc(
    const float* __restrict__ x, unsigned short* __restrict__ xb,
    const float* __restrict__ Wa, unsigned short* __restrict__ WaT,
    const float* __restrict__ Wp, unsigned short* __restrict__ WpT) {
    int bid = blockIdx.x, tid = threadIdx.x;
    if (bid < 4096) {
        int i = bid * 256 + tid;
        float4 v = ((const float4*)x)[i];
        ushort4 o;
        o.x = f2bf(v.x); o.y = f2bf(v.y); o.z = f2bf(v.z); o.w = f2bf(v.w);
        ((ushort4*)xb)[i] = o;
        return;
    }
    __shared__ float tile[32][33];
    const float* in;
    unsigned short* out;
    int N, b;
    if (bid < 4096 + 3072) {
        b = bid - 4096; in = Wa; out = WaT; N = 3072;
    } else {
        b = bid - 7168; in = Wp; out = WpT; N = 1024;
    }
    const int K = 1024;
    int kb = (b & 31) * 32, nb = (b >> 5) * 32;
    int tx = tid & 31, ty = tid >> 5;  // ty 0..7
    for (int r = 0; r < 4; r++)
        tile[ty + r * 8][tx] = in[(size_t)(kb + ty + r * 8) * N + nb + tx];
    __syncthreads();
    for (int r = 0; r < 4; r++)
        out[(size_t)(nb + ty + r * 8) * K + kb + tx] = f2bf(tile[tx][ty + r * 8]);
}

// ---------------- QKV GEMM: 128x128, BK=32, 3-buffer, 8 waves -------------
// R14 proven (~42us): 512 threads halve per-wave work -> 24 waves/CU
// (6/SIMD, 2x TLP vs R6). Same race-audited 3-buffer counted-vmcnt
// structure; per-wave vmcnt(2).
__global__ __launch_bounds__(512) void gemm_qkv(
    const unsigned short* __restrict__ A, const unsigned short* __restrict__ Bt,
    unsigned short* __restrict__ dK, unsigned short* __restrict__ dQ,
    unsigned short* __restrict__ dV) {
    const int K = 1024;
    const int NITER = K / 32;  // 32
    __shared__ unsigned short sA[3][128 * 32];
    __shared__ unsigned short sB[3][128 * 32];
    int tid = threadIdx.x, wave = tid >> 6, lane = tid & 63;
    int quad = lane >> 4, l16 = lane & 15;
    int wm = wave >> 1, wn = wave & 1;  // 4M x 2N wave grid
    int blockM = blockIdx.y * 128, blockN = blockIdx.x * 128;
    bool swapAB = (blockN >= 2048);  // V part: produce C^T

    const unsigned short* gA = A + (size_t)blockM * K;
    const unsigned short* gB = Bt + (size_t)blockN * K;

    int srow = wave * 16 + (lane >> 2);
    int scol = (lane & 3) * 8;
    const unsigned short* pa = gA + (size_t)srow * K + scol;
    const unsigned short* pb = gB + (size_t)srow * K + scol;
    int lo = (wave * 16) * 32;  // wave-uniform LDS offset (shorts)

    float4v acc[2][4] = {};
    int aoff = (wm * 32 + l16) * 32 + quad * 8;
    int boff = (wn * 64 + l16) * 32 + quad * 8;

    for (int t = 0; t < 2; t++) {
        int kb = t * 32;
        gload16(pa + kb, sA[t] + lo);
        gload16(pb + kb, sB[t] + lo);
    }
    asm volatile("s_waitcnt vmcnt(2)" ::: "memory");
    phase_barrier();

#pragma unroll
    for (int it = 0; it < NITER; it++) {
        int cur = it % 3;
        if (it + 2 < NITER) {
            int kb = (it + 2) * 32;
            int nb = (it + 2) % 3;
            gload16(pa + kb, sA[nb] + lo);
            gload16(pb + kb, sB[nb] + lo);
        }
        const unsigned short* cA = sA[cur];
        const unsigned short* cB = sB[cur];
        short8 af[2], bf[4];
        for (int i = 0; i < 2; i++)
            af[i] = *(const short8*)(cA + aoff + i * 16 * 32);
        for (int j = 0; j < 4; j++)
            bf[j] = *(const short8*)(cB + boff + j * 16 * 32);
        if (!swapAB) {
            for (int i = 0; i < 2; i++)
                for (int j = 0; j < 4; j++)
                    acc[i][j] = __builtin_amdgcn_mfma_f32_16x16x32_bf16(
                        af[i], bf[j], acc[i][j], 0, 0, 0);
        } else {
            for (int i = 0; i < 2; i++)
                for (int j = 0; j < 4; j++)
                    acc[i][j] = __builtin_amdgcn_mfma_f32_16x16x32_bf16(
                        bf[j], af[i], acc[i][j], 0, 0, 0);
        }
        if (it + 1 < NITER) {
            if (it + 2 < NITER) {
                asm volatile("s_waitcnt vmcnt(2)" ::: "memory");
            } else {
                asm volatile("s_waitcnt vmcnt(0)" ::: "memory");
            }
            phase_barrier();
        }
    }

    if (!swapAB) {
        const float QSCL = 0.18033688011112042f;  // 0.125 * log2(e)
        for (int i = 0; i < 2; i++)
            for (int j = 0; j < 4; j++)
                for (int r = 0; r < 4; r++) {
                    int m = blockM + wm * 32 + i * 16 + quad * 4 + r;
                    int n = blockN + wn * 64 + j * 16 + l16;
                    int part = n >> 10, c = n & 1023;
                    int h = c >> 6, d = c & 63;
                    int bb = m >> 11, t = m & 2047;
                    int bh = bb * NHEAD + h;
                    if (part == 0) {
                        dK[(((size_t)bh * T_SEQ + t) << 6) + d] = f2bf(acc[i][j][r]);
                    } else {
                        dQ[(((size_t)bh * T_SEQ + t) << 6) + d] =
                            f2bf(acc[i][j][r] * QSCL);
                    }
                }
    } else {
        for (int i = 0; i < 2; i++)
            for (int j = 0; j < 4; j++)
                for (int r = 0; r < 4; r++) {
                    int n = blockN + wn * 64 + j * 16 + quad * 4 + r;
                    int m = blockM + wm * 32 + i * 16 + l16;
                    int c = n & 1023;
                    int h = c >> 6, d = c & 63;
                    int bb = m >> 11, t = m & 2047;
                    int bh = bb * NHEAD + h;
                    dV[((size_t)bh * HDIM + d) * T_SEQ + t] = f2bf(acc[i][j][r]);
                }
    }
}

// ---------------- proj GEMM: 64x64 tile, BK=64, reg-prefetch --------------
// R0 proven FINAL (unchanged).
__global__ __launch_bounds__(256) void gemm_proj(
    const unsigned short* __restrict__ A, const unsigned short* __restrict__ Bt,
    const float* __restrict__ bias, float* __restrict__ out) {
    const int K = 1024;
    const int NITER = K / 64;
    __shared__ unsigned short sA[2][64 * PROW];
    __shared__ unsigned short sB[2][64 * PROW];
    int tid = threadIdx.x, wave = tid >> 6, lane = tid & 63;
    int quad = lane >> 4, l16 = lane & 15;
    int wm = wave >> 1, wn = wave & 1;
    int blockM = blockIdx.y * 64, blockN = blockIdx.x * 64;

    int srow = tid >> 3;      // 0..31
    int sseg = tid & 7;       // 0..7
    const unsigned short* gA0 = A + (size_t)(blockM + srow) * K + sseg * 8;
    const unsigned short* gA1 = gA0 + (size_t)32 * K;
    const unsigned short* gB0 = Bt + (size_t)(blockN + srow) * K + sseg * 8;
    const unsigned short* gB1 = gB0 + (size_t)32 * K;
    int so0 = srow * PROW + sseg * 8;
    int so1 = (srow + 32) * PROW + sseg * 8;

    float4v acc[2][2] = {};
    uint4 ra0, ra1, rb0, rb1;

    ra0 = *(const uint4*)gA0; ra1 = *(const uint4*)gA1;
    rb0 = *(const uint4*)gB0; rb1 = *(const uint4*)gB1;
    *(uint4*)(sA[0] + so0) = ra0;
    *(uint4*)(sA[0] + so1) = ra1;
    *(uint4*)(sB[0] + so0) = rb0;
    *(uint4*)(sB[0] + so1) = rb1;

    int aoff = (wm * 32 + l16) * PROW + quad * 8;
    int boff = (wn * 32 + l16) * PROW + quad * 8;

    for (int it = 0; it < NITER; it++) {
        int cur = it & 1;
        __syncthreads();
        if (it + 1 < NITER) {
            int kb = (it + 1) * 64;
            ra0 = *(const uint4*)(gA0 + kb); ra1 = *(const uint4*)(gA1 + kb);
            rb0 = *(const uint4*)(gB0 + kb); rb1 = *(const uint4*)(gB1 + kb);
        }
        const unsigned short* cA = sA[cur];
        const unsigned short* cB = sB[cur];
        short8 af[2][2], bf[2][2];
        for (int i = 0; i < 2; i++)
            for (int k = 0; k < 2; k++)
                af[i][k] = *(const short8*)(cA + aoff + i * 16 * PROW + k * 32);
        for (int j = 0; j < 2; j++)
            for (int k = 0; k < 2; k++)
                bf[j][k] = *(const short8*)(cB + boff + j * 16 * PROW + k * 32);
        for (int i = 0; i < 2; i++)
            for (int j = 0; j < 2; j++) {
                acc[i][j] = __builtin_amdgcn_mfma_f32_16x16x32_bf16(
                    af[i][0], bf[j][0], acc[i][j], 0, 0, 0);
                acc[i][j] = __builtin_amdgcn_mfma_f32_16x16x32_bf16(
                    af[i][1], bf[j][1], acc[i][j], 0, 0, 0);
            }
        if (it + 1 < NITER) {
            int nxt = cur ^ 1;
            *(uint4*)(sA[nxt] + so0) = ra0;
            *(uint4*)(sA[nxt] + so1) = ra1;
            *(uint4*)(sB[nxt] + so0) = rb0;
            *(uint4*)(sB[nxt] + so1) = rb1;
        }
    }

    for (int i = 0; i < 2; i++)
        for (int j = 0; j < 2; j++)
            for (int r = 0; r < 4; r++) {
                int m = blockM + wm * 32 + i * 16 + quad * 4 + r;
                int n = blockN + wn * 32 + j * 16 + l16;
                out[(size_t)m * CDIM + n] = acc[i][j][r] + bias[n];
            }
}

// ---------------- flash attention v12: K-split 8-wave ---------------------
// v9 inner math, but the K-loop is split across two 4-wave halves:
// waves 0-3 (half 0) process even K-tiles, waves 4-7 (half 1) odd K-tiles,
// SAME 64 q-rows. Fixed-max softmax (P = exp2(S-16), no running max) makes
// partials trivially mergeable: o_total = o0 + o1, lsum_total = l0 + l1.
// Block wall halves (max 16 steps vs 32); 1024 blocks at 2/CU LDS capacity
// = 2x oversubscribed -> dynamic re-dispatch rebalances the causal
// triangle (fixes the 22.8%-occupancy declining-residency tail).
// Uniform NI = ceil(nt/2) iterations keeps barriers convergent; inactive
// waves pass through. Each half dbuf-stages its own K/V (LDS 73.7KB;
// >64KB static proven launchable in R7).
__global__ __launch_bounds__(512) void attn_fwd(
    const unsigned short* __restrict__ Qp, const unsigned short* __restrict__ Kp,
    const unsigned short* __restrict__ Vt, unsigned short* __restrict__ att) {
    __shared__ unsigned short sK[2][2][64 * 72];  // [half][dbuf]
    __shared__ unsigned short sV[2][2][64 * 72];
    int tid = threadIdx.x, wave = tid >> 6, lane = tid & 63;
    int quad = lane >> 4, l16 = lane & 15;
    int half = wave >> 2, qw = wave & 3;
    int bh = blockIdx.x;
    int bb = bh >> 4, h = bh & 15;
    size_t baseQ = (size_t)bh * T_SEQ * HDIM;  // [t][d]
    size_t baseV = (size_t)bh * HDIM * T_SEQ;  // [d][t]
    int htid = tid & 255;                      // half-local thread id
    int row4 = htid >> 2, seg = htid & 3;

    int xt = 31 - blockIdx.y;  // LPT: longest blocks dispatch first
    int qb = xt * 64;
    int qrow = qb + qw * 16 + l16;

    const unsigned short* qr = Qp + baseQ + (size_t)qrow * HDIM;
    short8 qf0 = *(const short8*)(qr + quad * 8);
    short8 qf1 = *(const short8*)(qr + 32 + quad * 8);

    float4v o[4] = {};
    float lsum = 0.f;
    int nt = xt + 1;
    int NI = (nt + 1) >> 1;  // uniform iteration count across both halves

    const float4v NEG16 = {-16.f, -16.f, -16.f, -16.f};

    uint4 ka, kb2, va, vb;
    // prologue: each half stages its first tile (t0 = half) into dbuf 0
    if (half < nt) {
        const unsigned short* gk =
            Kp + baseQ + (size_t)(half * 64 + row4) * HDIM + seg * 16;
        const unsigned short* gv =
            Vt + baseV + (size_t)row4 * T_SEQ + half * 64 + seg * 16;
        ka = *(const uint4*)gk; kb2 = *(const uint4*)(gk + 8);
        va = *(const uint4*)gv; vb = *(const uint4*)(gv + 8);
        *(uint4*)(sK[half][0] + row4 * 72 + seg * 16) = ka;
        *(uint4*)(sK[half][0] + row4 * 72 + seg * 16 + 8) = kb2;
        *(uint4*)(sV[half][0] + row4 * 72 + seg * 16) = va;
        *(uint4*)(sV[half][0] + row4 * 72 + seg * 16 + 8) = vb;
    }

    for (int i = 0; i < NI; i++) {
        int t = 2 * i + half;  // this wave's tile (wave-uniform)
        int cur = i & 1;
        __syncthreads();
        int tn = t + 2;
        if (tn < nt) {
            const unsigned short* gk =
                Kp + baseQ + (size_t)(tn * 64 + row4) * HDIM + seg * 16;
            const unsigned short* gv =
                Vt + baseV + (size_t)row4 * T_SEQ + tn * 64 + seg * 16;
            ka = *(const uint4*)gk; kb2 = *(const uint4*)(gk + 8);
            va = *(const uint4*)gv; vb = *(const uint4*)(gv + 8);
        }

        if (t < nt) {
            const unsigned short* cK = sK[half][cur];
            const unsigned short* cV = sV[half][cur];
            float4v s[4];
            __builtin_amdgcn_s_setprio(1);
            for (int sub = 0; sub < 4; sub++) {
                short8 kf0 =
                    *(const short8*)(cK + (sub * 16 + l16) * 72 + quad * 8);
                short8 kf1 =
                    *(const short8*)(cK + (sub * 16 + l16) * 72 + 32 + quad * 8);
                float4v z = NEG16;  // fixed-max -16 folded into C-init
                z = __builtin_amdgcn_mfma_f32_16x16x32_bf16(kf0, qf0, z, 0, 0, 0);
                z = __builtin_amdgcn_mfma_f32_16x16x32_bf16(kf1, qf1, z, 0, 0, 0);
                s[sub] = z;
            }
            __builtin_amdgcn_s_setprio(0);

            float e[16];
            bool need_mask = (t * 64 + 63) > (qb + qw * 16);  // wave-uniform
            if (need_mask) {
                int kgb = t * 64 + quad * 4;
                for (int sub = 0; sub < 4; sub++)
                    for (int r = 0; r < 4; r++) {
                        float v = __builtin_amdgcn_exp2f(s[sub][r]);
                        v = (kgb + sub * 16 + r <= qrow) ? v : 0.0f;
                        e[sub * 4 + r] = v;
                        lsum += v;
                    }
            } else {
                for (int sub = 0; sub < 4; sub++)
                    for (int r = 0; r < 4; r++) {
                        float v = __builtin_amdgcn_exp2f(s[sub][r]);
                        e[sub * 4 + r] = v;
                        lsum += v;
                    }
            }

            __builtin_amdgcn_s_setprio(1);
            for (int sub = 0; sub < 4; sub++) {
                unsigned lo, hi;
                asm("v_cvt_pk_bf16_f32 %0, %1, %2"
                    : "=v"(lo) : "v"(e[sub * 4 + 0]), "v"(e[sub * 4 + 1]));
                asm("v_cvt_pk_bf16_f32 %0, %1, %2"
                    : "=v"(hi) : "v"(e[sub * 4 + 2]), "v"(e[sub * 4 + 3]));
                uint2 packed = {lo, hi};
                short4v pf = __builtin_bit_cast(short4v, packed);
                for (int dc = 0; dc < 4; dc++) {
                    short4v vf = *(const short4v*)(
                        cV + (dc * 16 + l16) * 72 + sub * 16 + quad * 4);
                    o[dc] = __builtin_amdgcn_mfma_f32_16x16x16bf16_1k(
                        vf, pf, o[dc], 0, 0, 0);
                }
            }
            __builtin_amdgcn_s_setprio(0);
        }

        if (tn < nt) {
            int nxt = cur ^ 1;
            *(uint4*)(sK[half][nxt] + row4 * 72 + seg * 16) = ka;
            *(uint4*)(sK[half][nxt] + row4 * 72 + seg * 16 + 8) = kb2;
            *(uint4*)(sV[half][nxt] + row4 * 72 + seg * 16) = va;
            *(uint4*)(sV[half][nxt] + row4 * 72 + seg * 16 + 8) = vb;
        }
    }

    // per-half row reduction (combine the 4 quads)
    lsum += __shfl_xor(lsum, 16);
    lsum += __shfl_xor(lsum, 32);

    // merge half 1 -> half 0 via LDS overlay on sK (20-float stride, 16B
    // aligned; 4*64*20*4B = 20.5KB <= 36.9KB region)
    float* mb = (float*)sK;
    float* slot = mb + (size_t)(qw * 64 + lane) * 20;
    __syncthreads();  // loop-phase LDS reads done before overlay writes
    if (half == 1) {
        for (int dc = 0; dc < 4; dc++) *(float4v*)(slot + dc * 4) = o[dc];
        slot[16] = lsum;
    }
    __syncthreads();
    unsigned short* rp = sV[0][0];  // repack area (4 waves x 1152 shorts)
    if (half == 0) {
        for (int dc = 0; dc < 4; dc++) o[dc] += *(const float4v*)(slot + dc * 4);
        lsum += slot[16];
        float inv = 1.0f / lsum;
        for (int dc = 0; dc < 4; dc++) {
            short4v ov;
            for (int r = 0; r < 4; r++) ov[r] = (short)f2bf(o[dc][r] * inv);
            *(short4v*)(rp + qw * 1152 + l16 * 72 + dc * 16 + quad * 4) = ov;
        }
    }
    __syncthreads();
    if (half == 0) {
        int orow = lane >> 2, oseg = lane & 3;
        uint4 a = *(const uint4*)(rp + qw * 1152 + orow * 72 + oseg * 16);
        uint4 b = *(const uint4*)(rp + qw * 1152 + orow * 72 + oseg * 16 + 8);
        unsigned short* dst = att +
            (size_t)(bb * T_SEQ + qb + qw * 16 + orow) * CDIM + h * HDIM +
            oseg * 16;
        *(uint4*)dst = a;
        *(uint4*)(dst + 8) = b;
    }
}

// ---------------- launch ----------------
extern "C" void kernel_launch(void* const* d_in, const int* in_sizes, int n_in,
                              void* d_out, int out_size, void* d_ws, size_t ws_size,
                              hipStream_t stream) {
    const float* x      = (const float*)d_in[0];   // [2,2048,1024]
    const float* W_attn = (const float*)d_in[1];   // [1024,3072]
    const float* W_proj = (const float*)d_in[2];   // [1024,1024]
    const float* b_proj = (const float*)d_in[3];   // [1024]
    float* out = (float*)d_out;                    // [2,2048,1024]

    unsigned short* xb   = (unsigned short*)d_ws;          // 4096*1024
    unsigned short* WaT  = xb  + 4096 * 1024;              // 3072*1024 (transposed)
    unsigned short* WpT  = WaT + 3072 * 1024;              // 1024*1024 (transposed)
    unsigned short* Karr = WpT + 1024 * 1024;              // [B,H,T,64]
    unsigned short* Qarr = Karr + 2 * 16 * 2048 * 64;      // [B,H,T,64] pre-scaled
    unsigned short* Varr = Qarr + 2 * 16 * 2048 * 64;      // [B,H,64,T] transposed
    unsigned short* attb = Varr + 2 * 16 * 2048 * 64;      // 4096*1024

    preproc<<<8192, 256, 0, stream>>>(x, xb, W_attn, WaT, W_proj, WpT);
    gemm_qkv<<<dim3(24, 32), 512, 0, stream>>>(xb, WaT, Karr, Qarr, Varr);
    attn_fwd<<<dim3(32, 32), 512, 0, stream>>>(Qarr, Karr, Varr, attb);
    gemm_proj<<<dim3(16, 64), 256, 0, stream>>>(attb, WpT, b_proj, out);
}